// Round 7
// baseline (136.915 us; speedup 1.0000x reference)
//
#include <hip/hip_runtime.h>
#include <math.h>

#define Bsz 2048
#define Lsz 1024
#define SW  8   // waves (batches) per scan block

// ws layout (float offsets)
#define OFF_GC  0        // c_v * G[v][:]  65x64 (row 64 = zeros, dummy token)
#define OFF_PG  4160     // g_v * (h_v @ (read_w@out_w))  64x64
#define OFF_H   8256     // h table staging 64x64 (prep1 -> prep2, never overwritten)
#define OFF_WC  12352    // read_w @ out_w  64x64
#define OFF_GV  16448    // g per token
#define OFF_CI  16512    // denom/g per token (1/c)
#define OFF_C   16576    // g/denom per token (c)
#define OFF_BC  16640    // read_b@out_w + out_b
// total 16704 floats = 66.8 KB

__device__ __forceinline__ float __rlf(float v, int i) {
    return __int_as_float(__builtin_amdgcn_readlane(__float_as_int(v), i));
}

// ---------------- prep1: per-token h/g/c (blocks 0..63), Wc rows (64..127), bc (128)
__global__ __launch_bounds__(128) void prep1_kernel(
    const float* __restrict__ embed_W, const float* __restrict__ ff_w1, const float* __restrict__ ff_b1,
    const float* __restrict__ ff_w2, const float* __restrict__ ff_b2, const float* __restrict__ ln_g,
    const float* __restrict__ ln_b, const float* __restrict__ gate_w1, const float* __restrict__ gate_b1,
    const float* __restrict__ gate_w2, const float* __restrict__ gate_b2, const float* __restrict__ read_w,
    const float* __restrict__ read_b, const float* __restrict__ out_w, const float* __restrict__ out_b,
    float* __restrict__ ws)
{
    const int tid = threadIdx.x;
    const int blk = blockIdx.x;
    if (blk < 64) {
        const int v = blk;
        __shared__ float z[128];
        __shared__ float hsh[64];
        const float* Ev = embed_W + (v << 6);
        float a = ff_b1[tid];
        #pragma unroll
        for (int i = 0; i < 64; ++i) a = fmaf(Ev[i], ff_w1[i * 128 + tid], a);
        z[tid] = fmaxf(a, 0.0f);
        __syncthreads();
        if (tid < 64) {   // wave 0 only
            float x = Ev[tid] + ff_b2[tid];
            #pragma unroll
            for (int j = 0; j < 128; ++j) x = fmaf(z[j], ff_w2[j * 64 + tid], x);
            float mu = x;
            #pragma unroll
            for (int off = 32; off > 0; off >>= 1) mu += __shfl_xor(mu, off);
            mu *= (1.0f / 64.0f);
            const float dd = x - mu;
            float var = dd * dd;
            #pragma unroll
            for (int off = 32; off > 0; off >>= 1) var += __shfl_xor(var, off);
            var *= (1.0f / 64.0f);
            const float rstd = rsqrtf(var + 1e-5f);
            const float hv = fmaf(dd * rstd, ln_g[tid], ln_b[tid]);
            hsh[tid] = hv;
            ws[OFF_H + (v << 6) + tid] = hv;
            float dn = hv * hv;
            #pragma unroll
            for (int off = 32; off > 0; off >>= 1) dn += __shfl_xor(dn, off);
            dn += 1e-6f;
            float a2 = 0.0f;
            if (tid < 16) {
                float um = gate_b1[tid];
                #pragma unroll
                for (int i = 0; i < 64; ++i) um = fmaf(hsh[i], gate_w1[i * 16 + tid], um);
                a2 = fmaxf(um, 0.0f) * gate_w2[tid];
            }
            #pragma unroll
            for (int off = 8; off > 0; off >>= 1) a2 += __shfl_xor(a2, off);
            if (tid == 0) {
                a2 += gate_b2[0];
                const float g = 1.0f / (1.0f + expf(-a2));
                ws[OFF_GV + v] = g;
                ws[OFF_C  + v] = g / dn;
                ws[OFF_CI + v] = dn / g;
            }
        }
    } else if (blk < 128) {
        const int j = blk - 64;
        if (tid < 64) {
            float a = 0.0f;
            #pragma unroll
            for (int m = 0; m < 64; ++m) a = fmaf(read_w[(j << 6) + m], out_w[(m << 6) + tid], a);
            ws[OFF_WC + (j << 6) + tid] = a;
        }
    } else {
        if (tid < 64) {
            float a = out_b[tid];
            #pragma unroll
            for (int jj = 0; jj < 64; ++jj) a = fmaf(read_b[jj], out_w[(jj << 6) + tid], a);
            ws[OFF_BC + tid] = a;
        }
    }
}

// ---------------- prep2: Gc rows (blocks 0..63), Pg rows (64..127), dummy row (128)
// Reads OFF_H (never written here) -> no inter-block race.
__global__ __launch_bounds__(64) void prep2_kernel(float* __restrict__ ws)
{
    const int tid = threadIdx.x;
    const int blk = blockIdx.x;
    if (blk == 128) { ws[OFF_GC + 64 * 64 + tid] = 0.0f; return; }
    __shared__ float tT[65 * 64];   // tT[j*65+w] = h[w][j] (padded)
    for (int idx = tid; idx < 4096; idx += 64) {
        const int w = idx >> 6, j = idx & 63;
        tT[j * 65 + w] = ws[OFF_H + idx];
    }
    __syncthreads();
    if (blk < 64) {
        const int v = blk;
        const float cv = ws[OFF_C + v];
        float a = 0.0f;
        #pragma unroll
        for (int j = 0; j < 64; ++j) a = fmaf(tT[j * 65 + v], tT[j * 65 + tid], a);
        ws[OFF_GC + (v << 6) + tid] = cv * a;
    } else {
        const int v = blk - 64;
        const float gv = ws[OFF_GV + v];
        float a = 0.0f;
        #pragma unroll
        for (int j = 0; j < 64; ++j)
            a = fmaf(tT[j * 65 + v], ws[OFF_WC + (j << 6) + tid], a);
        ws[OFF_PG + (v << 6) + tid] = gv * a;  // g folded into Pg
    }
}

// ---------------- scan: one wave per batch; tokens in 4 VGPRs, 8-step batches,
// lgkm waits always expressible (peak 16 outstanding, wait target = oldest).
__global__ __launch_bounds__(SW * 64) void scan_kernel(const int* __restrict__ seq,
                                                       const float* __restrict__ ws,
                                                       float* __restrict__ out)
{
    __shared__ float ldsGc[65 * 64];
    __shared__ float ldsPg[64 * 64];

    const int tid  = threadIdx.x;
    const int wave = tid >> 6;
    const int lane = tid & 63;
    const int b    = blockIdx.x * SW + wave;

    // token loads first (overlap with table staging)
    const int4* ts = (const int4*)(seq + (size_t)b * Lsz);
    const int4 q0 = ts[lane], q1 = ts[64 + lane], q2 = ts[128 + lane], q3 = ts[192 + lane];

    {
        const float4* s1 = (const float4*)(ws + OFF_GC);
        float4* d1 = (float4*)ldsGc;
        for (int i = tid; i < 1040; i += SW * 64) d1[i] = s1[i];
        const float4* s2 = (const float4*)(ws + OFF_PG);
        float4* d2 = (float4*)ldsPg;
        for (int i = tid; i < 1024; i += SW * 64) d2[i] = s2[i];
    }

    // pack: byte j of lane l of tvp = token 256p + 4l + j
    int tv0 = q0.x | (q0.y << 8) | (q0.z << 16) | (q0.w << 24);
    int tv1 = q1.x | (q1.y << 8) | (q1.z << 16) | (q1.w << 24);
    int tv2 = q2.x | (q2.y << 8) | (q2.z << 16) | (q2.w << 24);
    int tv3 = q3.x | (q3.y << 8) | (q3.z << 16) | (q3.w << 24);

    // step 1023 is the query -> replace with dummy token 64 (Gc row 64 = 0)
    const int tokL = (__builtin_amdgcn_readlane(tv3, 63) >> 24) & 0x7F;
    if (lane == 63) tv3 = (tv3 & 0x00FFFFFF) | (64 << 24);

    __syncthreads();

    float D = ldsGc[(tokL << 6) + lane] * ws[OFF_CI + tokL];   // D_v = G[tokL][v]
    float u = 0.0f;

    int   tk1[8], tk0[8], nk1[8], nk0[8];
    float gA[8], gB[8];

    auto EXT = [&](int wh, int wl, int* tk) {
        tk[0] = (wh >> 24) & 0x7F; tk[1] = (wh >> 16) & 0x7F;
        tk[2] = (wh >>  8) & 0x7F; tk[3] =  wh        & 0x7F;
        tk[4] = (wl >> 24) & 0x7F; tk[5] = (wl >> 16) & 0x7F;
        tk[6] = (wl >>  8) & 0x7F; tk[7] =  wl        & 0x7F;
    };
    auto ISSUE = [&](const int* tk, float* g) {
        #pragma unroll
        for (int k = 0; k < 8; ++k) g[k] = ldsGc[(tk[k] << 6) + lane];
    };
    auto STEP = [&](const int* tk, const float* g) {
        #pragma unroll
        for (int k = 0; k < 8; ++k) {
            const float d = __rlf(D, tk[k]);
            u += (lane == tk[k]) ? d : 0.0f;
            D = fmaf(-d, g[k], D);
        }
    };

    // batches m = 127..0 cover steps 8m+7..8m (descending). Batch m uses packed
    // words 2m+1, 2m = lanes (4u+3..4u) of tv[p], where m = 32p + 2u + {1,0}.
    // prologue: pair (p=3, u=15) -> m1=127, m0=126
    EXT(__builtin_amdgcn_readlane(tv3, 63), __builtin_amdgcn_readlane(tv3, 62), tk1);
    EXT(__builtin_amdgcn_readlane(tv3, 61), __builtin_amdgcn_readlane(tv3, 60), tk0);
    ISSUE(tk1, gA);

    #pragma unroll
    for (int p = 3; p >= 0; --p) {
        const int tvp = (p == 3) ? tv3 : (p == 2) ? tv2 : (p == 1) ? tv1 : tv0;
        for (int uu = 15; uu >= 1; --uu) {
            ISSUE(tk0, gB);
            STEP(tk1, gA);           // gA loaded a full iteration ago
            EXT(__builtin_amdgcn_readlane(tvp, 4 * uu - 1),
                __builtin_amdgcn_readlane(tvp, 4 * uu - 2), nk1);
            EXT(__builtin_amdgcn_readlane(tvp, 4 * uu - 3),
                __builtin_amdgcn_readlane(tvp, 4 * uu - 4), nk0);
            ISSUE(nk1, gA);
            STEP(tk0, gB);
            #pragma unroll
            for (int k = 0; k < 8; ++k) { tk1[k] = nk1[k]; tk0[k] = nk0[k]; }
        }
        // peeled u=0: m1 = 32p+1, m0 = 32p
        ISSUE(tk0, gB);
        STEP(tk1, gA);
        if (p > 0) {
            // extract into nk (NOT tk0 -- tk0's STEP hasn't run yet!)
            const int tvn = (p == 3) ? tv2 : (p == 2) ? tv1 : tv0;
            EXT(__builtin_amdgcn_readlane(tvn, 63), __builtin_amdgcn_readlane(tvn, 62), nk1);
            EXT(__builtin_amdgcn_readlane(tvn, 61), __builtin_amdgcn_readlane(tvn, 60), nk0);
            ISSUE(nk1, gA);
            STEP(tk0, gB);
            #pragma unroll
            for (int k = 0; k < 8; ++k) { tk1[k] = nk1[k]; tk0[k] = nk0[k]; }
        } else {
            STEP(tk0, gB);
        }
    }

    // epilogue: logits = u @ Pg + bc (g pre-folded into Pg)
    float acc = ws[OFF_BC + lane];
    #pragma unroll 16
    for (int v = 0; v < 64; ++v)
        acc = fmaf(__rlf(u, v), ldsPg[(v << 6) + lane], acc);
    out[(size_t)b * 64 + lane] = acc;
}

extern "C" void kernel_launch(void* const* d_in, const int* in_sizes, int n_in,
                              void* d_out, int out_size, void* d_ws, size_t ws_size,
                              hipStream_t stream) {
    const int*   seq     = (const int*)  d_in[0];
    const float* embed_W = (const float*)d_in[1];
    const float* ff_w1   = (const float*)d_in[2];
    const float* ff_b1   = (const float*)d_in[3];
    const float* ff_w2   = (const float*)d_in[4];
    const float* ff_b2   = (const float*)d_in[5];
    const float* ln_g    = (const float*)d_in[6];
    const float* ln_b    = (const float*)d_in[7];
    const float* gate_w1 = (const float*)d_in[8];
    const float* gate_b1 = (const float*)d_in[9];
    const float* gate_w2 = (const float*)d_in[10];
    const float* gate_b2 = (const float*)d_in[11];
    const float* read_w  = (const float*)d_in[12];
    const float* read_b  = (const float*)d_in[13];
    const float* out_w   = (const float*)d_in[14];
    const float* out_b   = (const float*)d_in[15];
    float* ws  = (float*)d_ws;
    float* out = (float*)d_out;

    hipLaunchKernelGGL(prep1_kernel, dim3(129), dim3(128), 0, stream,
                       embed_W, ff_w1, ff_b1, ff_w2, ff_b2, ln_g, ln_b,
                       gate_w1, gate_b1, gate_w2, gate_b2, read_w, read_b,
                       out_w, out_b, ws);
    hipLaunchKernelGGL(prep2_kernel, dim3(129), dim3(64), 0, stream, ws);
    hipLaunchKernelGGL(scan_kernel, dim3(Bsz / SW), dim3(SW * 64), 0, stream,
                       seq, ws, out);
}